// Round 1
// baseline (102.955 us; speedup 1.0000x reference)
//
#include <hip/hip_runtime.h>
#include <hip/hip_bf16.h>

// Problem: B=16384, D=4096, fp32.
// out = mean_i( sum_j w[j] * |in[i,j] - t[i,j]| )
// Memory-bound: 512 MB of HBM reads -> ~85 us floor at 6.3 TB/s.

#define B_ROWS 16384
#define D_COLS 4096
#define NV4    ((B_ROWS * (long long)D_COLS) / 4)   // total float4 elements
#define D4     (D_COLS / 4)                          // 1024 float4 per row
#define NBLK   2048
#define NTHR   256

__global__ __launch_bounds__(NTHR) void l1w_partial(
    const float4* __restrict__ a,
    const float4* __restrict__ b,
    const float4* __restrict__ w4,
    float* __restrict__ partial)
{
    long long tid    = (long long)blockIdx.x * blockDim.x + threadIdx.x;
    long long stride = (long long)gridDim.x * blockDim.x;

    float acc = 0.0f;
    for (long long t = tid; t < NV4; t += stride) {
        float4 av = a[t];
        float4 bv = b[t];
        float4 wv = w4[t & (D4 - 1)];   // j4 = t % 1024 since D divides row-aligned float4s
        acc = fmaf(wv.x, fabsf(av.x - bv.x), acc);
        acc = fmaf(wv.y, fabsf(av.y - bv.y), acc);
        acc = fmaf(wv.z, fabsf(av.z - bv.z), acc);
        acc = fmaf(wv.w, fabsf(av.w - bv.w), acc);
    }

    // wave-64 reduce
    #pragma unroll
    for (int off = 32; off > 0; off >>= 1)
        acc += __shfl_down(acc, off, 64);

    __shared__ float s[NTHR / 64];
    int lane = threadIdx.x & 63;
    int wid  = threadIdx.x >> 6;
    if (lane == 0) s[wid] = acc;
    __syncthreads();
    if (threadIdx.x == 0) {
        float r = s[0];
        #pragma unroll
        for (int i = 1; i < NTHR / 64; ++i) r += s[i];
        partial[blockIdx.x] = r;
    }
}

__global__ __launch_bounds__(NTHR) void l1w_final(
    const float* __restrict__ partial,
    float* __restrict__ out,
    int n)
{
    float acc = 0.0f;
    for (int i = threadIdx.x; i < n; i += NTHR)
        acc += partial[i];

    #pragma unroll
    for (int off = 32; off > 0; off >>= 1)
        acc += __shfl_down(acc, off, 64);

    __shared__ float s[NTHR / 64];
    int lane = threadIdx.x & 63;
    int wid  = threadIdx.x >> 6;
    if (lane == 0) s[wid] = acc;
    __syncthreads();
    if (threadIdx.x == 0) {
        float r = s[0];
        #pragma unroll
        for (int i = 1; i < NTHR / 64; ++i) r += s[i];
        out[0] = r * (1.0f / (float)B_ROWS);
    }
}

extern "C" void kernel_launch(void* const* d_in, const int* in_sizes, int n_in,
                              void* d_out, int out_size, void* d_ws, size_t ws_size,
                              hipStream_t stream) {
    const float4* a  = (const float4*)d_in[0];   // inputs  [B, D]
    const float4* b  = (const float4*)d_in[1];   // targets [B, D]
    const float4* w4 = (const float4*)d_in[2];   // w [D]
    float* partial   = (float*)d_ws;             // NBLK floats (8 KB)
    float* out       = (float*)d_out;

    l1w_partial<<<NBLK, NTHR, 0, stream>>>(a, b, w4, partial);
    l1w_final<<<1, NTHR, 0, stream>>>(partial, out, NBLK);
}